// Round 1
// baseline (99.591 us; speedup 1.0000x reference)
//
#include <hip/hip_runtime.h>

// loss = mean over all elements of (sigmoid(x) - t)^2 * ((1-t) + (x<=0 ? 1 : 0))
// distance_transform(m) == 1 - m for binary m (center tap of the 3x3 ones conv
// guarantees iteration 1 returns `inverted`; iteration 2 breaks). dt^2 = 1-t
// since t in {0,1}; preds = (sigmoid(x)>0.5) = (x>0).
//
// LESSONS (counter-verified):
//  R2: __threadfence() per block = per-XCD L2 wb+inv -> ~80us idle-pipe stall.
//  R3/R4: N-deep same-address atomicAdd (result consumed) serializes at
//      ~11.5ns each and blocks retirement: 4096 deep -> +45us. The fan-out
//      accum atomics were fine; the single shared counter was not.
//  => Two plain kernels with NO atomics/fences is the fastest structure here.
//  R5 (this session, counter analysis): timed region = 2 x ~41.2us harness
//      poison fills of the 256 MiB workspace (fillBufferAligned, 262144 KB
//      @ ~6.5 TB/s -- all five top-5 dispatches) + ~14us of our kernels.
//      The fills are harness-structural; only the ~14us kernel portion is
//      controllable, vs a 67.1MB / 6.3TB/s ~= 10.7us HBM floor.
//
// kernel1: 2048 blocks x 256 thr (8 blk/CU = 32 waves/CU, one dispatch round),
//   ONE super-iteration issuing all 8 independent nontemporal float4 loads
//   (4 strided pairs) before any dependent compute -> max loads-in-flight,
//   wave+LDS reduce, plain store of one partial per block.
// kernel2: one 64-lane wave reduces 2048 partials via float4 loads + shuffle
//   (no LDS, no __syncthreads), double accum, writes the mean.
// Visibility via kernel boundary; no memset nodes needed (all ws slots written
// by kernel1 before kernel2 reads; out written unconditionally).

typedef float v4f __attribute__((ext_vector_type(4)));

#define NTHREADS 256
#define NBLOCKS  2048
#define FTHREADS 64

__device__ __forceinline__ float loss_term(float x, float t) {
    float p = 1.0f / (1.0f + __expf(-x));
    float d = p - t;
    float w = (1.0f - t) + (x > 0.0f ? 0.0f : 1.0f);
    return d * d * w;
}

__device__ __forceinline__ float loss4(v4f x, v4f t) {
    return loss_term(x.x, t.x) + loss_term(x.y, t.y) +
           loss_term(x.z, t.z) + loss_term(x.w, t.w);
}

__global__ __launch_bounds__(NTHREADS) void hausdorff_partial(
        const float* __restrict__ logits,
        const float* __restrict__ targets,
        float* __restrict__ partial,
        int n) {
    const int tid    = blockIdx.x * NTHREADS + threadIdx.x;
    const int stride = NBLOCKS * NTHREADS;      // 524288 threads
    const int n4     = n >> 2;                  // 2097152 for n = 8M

    const v4f* __restrict__ x4 = (const v4f*)logits;
    const v4f* __restrict__ t4 = (const v4f*)targets;

    float acc = 0.0f;
    int i = tid;

    // Main: 4 strided float4 pairs per super-iteration. All 8 loads are
    // independent and nontemporal (pure streaming, zero reuse) so the
    // compiler issues them back-to-back before the first s_waitcnt.
    // For n = 8M this loop runs exactly once per thread (4*stride == n4).
    for (; i + 3 * stride < n4; i += 4 * stride) {
        v4f x0 = __builtin_nontemporal_load(&x4[i]);
        v4f x1 = __builtin_nontemporal_load(&x4[i +     stride]);
        v4f x2 = __builtin_nontemporal_load(&x4[i + 2 * stride]);
        v4f x3 = __builtin_nontemporal_load(&x4[i + 3 * stride]);
        v4f t0 = __builtin_nontemporal_load(&t4[i]);
        v4f t1 = __builtin_nontemporal_load(&t4[i +     stride]);
        v4f t2 = __builtin_nontemporal_load(&t4[i + 2 * stride]);
        v4f t3 = __builtin_nontemporal_load(&t4[i + 3 * stride]);
        acc += loss4(x0, t0);
        acc += loss4(x1, t1);
        acc += loss4(x2, t2);
        acc += loss4(x3, t3);
    }
    // Remainder float4s (empty for n = 8M, kept for generality)
    for (; i < n4; i += stride)
        acc += loss4(x4[i], t4[i]);
    // Scalar tail (empty for n = 8M)
    for (int j = (n4 << 2) + tid; j < n; j += stride)
        acc += loss_term(logits[j], targets[j]);

    #pragma unroll
    for (int off = 32; off > 0; off >>= 1)
        acc += __shfl_down(acc, off, 64);

    __shared__ float smem[NTHREADS / 64];
    const int lane = threadIdx.x & 63;
    const int wave = threadIdx.x >> 6;
    if (lane == 0) smem[wave] = acc;
    __syncthreads();

    if (threadIdx.x == 0) {
        float s = 0.0f;
        #pragma unroll
        for (int w = 0; w < NTHREADS / 64; ++w) s += smem[w];
        partial[blockIdx.x] = s;    // plain store — no atomic, no fence
    }
}

// One wave (64 lanes): float4 loads of the 2048 partials, shuffle-only
// double reduce. No LDS, no __syncthreads — wave-synchronous.
__global__ __launch_bounds__(FTHREADS) void hausdorff_final(
        const float* __restrict__ partial,
        float* __restrict__ out,
        int nblocks, double inv_n) {
    const v4f* __restrict__ p4 = (const v4f*)partial;
    const int n4 = nblocks >> 2;                // 512

    double acc = 0.0;
    for (int i = threadIdx.x; i < n4; i += FTHREADS) {   // 8 iterations
        v4f v = p4[i];
        acc += (double)v.x + (double)v.y + (double)v.z + (double)v.w;
    }
    for (int j = (n4 << 2) + threadIdx.x; j < nblocks; j += FTHREADS)
        acc += (double)partial[j];              // tail: empty for 2048

    #pragma unroll
    for (int off = 32; off > 0; off >>= 1)
        acc += __shfl_down(acc, off, 64);

    if (threadIdx.x == 0) out[0] = (float)(acc * inv_n);
}

extern "C" void kernel_launch(void* const* d_in, const int* in_sizes, int n_in,
                              void* d_out, int out_size, void* d_ws, size_t ws_size,
                              hipStream_t stream) {
    const float* logits  = (const float*)d_in[0];
    const float* targets = (const float*)d_in[1];
    float* out = (float*)d_out;
    float* partial = (float*)d_ws;

    const int n = in_sizes[0];  // 8*1024*1024

    hausdorff_partial<<<NBLOCKS, NTHREADS, 0, stream>>>(logits, targets, partial, n);
    hausdorff_final<<<1, FTHREADS, 0, stream>>>(partial, out, NBLOCKS, 1.0 / (double)n);
}